// Round 1
// baseline (673.747 us; speedup 1.0000x reference)
//
#include <hip/hip_runtime.h>
#include <hip/hip_bf16.h>

// ---------------------------------------------------------------------------
// GCN graph classifier: 3x GCNConv(128->128) + ReLU, mean-pool(64), linear(10)
// Strategy:
//   * Build CSR (by dst) + sym-norm once per call (graph identical across layers)
//   * Per layer: agg = A_norm * x  (pull-based gather, wave per node),
//                x' = relu(agg @ W + b)  (fp32 tiled GEMM, vector ALU)
//   * Pool: batch is sorted -> per-block running sums, atomic flush per boundary
//   * Final: (sums @ Wlin)/cnt + blin  -> out[64][10]
// ---------------------------------------------------------------------------

#define HID 128
#define NGRAPH 64

// runtime int32/int64 index accessor (reference declares int64; JAX default is
// int32 — detect on device and branch)
__device__ __forceinline__ int idx_at(const void* p, long long i, int f64) {
    if (f64) return (int)((const long long*)p)[i];
    return ((const int*)p)[i];
}

// Detect whether index arrays are int64: sample odd 32-bit words of edge_index;
// for little-endian int64 with values < 2^31 they are all zero.
__global__ void detect_kernel(const int* __restrict__ ei, int* __restrict__ flag) {
    __shared__ int cnt;
    if (threadIdx.x == 0) cnt = 0;
    __syncthreads();
    int z = 0;
    for (int i = threadIdx.x; i < 2048; i += 256)
        if (ei[2 * i + 1] == 0) z++;
    atomicAdd(&cnt, z);
    __syncthreads();
    if (threadIdx.x == 0) *flag = (cnt > 1024) ? 1 : 0;
}

__global__ void init_kernel(int* __restrict__ counts, float* __restrict__ pooled,
                            float* __restrict__ gcnt, int N) {
    int i = blockIdx.x * blockDim.x + threadIdx.x;
    if (i < N) counts[i] = 0;
    if (i < NGRAPH * HID) pooled[i] = 0.f;
    if (i < NGRAPH) gcnt[i] = 0.f;
}

__global__ void hist_kernel(const void* __restrict__ ei, const int* __restrict__ flag,
                            int* __restrict__ counts, int E, int N) {
    int e = blockIdx.x * blockDim.x + threadIdx.x;
    if (e >= E) return;
    int f64 = *flag;
    int d = idx_at(ei, (long long)E + e, f64);
    if ((unsigned)d < (unsigned)N) atomicAdd(&counts[d], 1);
}

// Single-block exclusive scan over counts[N] -> rowstart[N+1]; also fills
// cursor (copy of rowstart) and dinv = rsqrt(deg) with deg = counts+1 (self loop).
__global__ __launch_bounds__(1024) void scan_kernel(const int* __restrict__ counts,
                                                    int* __restrict__ rowstart,
                                                    int* __restrict__ cursor,
                                                    float* __restrict__ dinv, int N) {
    __shared__ int sums[1024];
    int t = threadIdx.x;
    int chunk = (N + 1023) >> 10;
    int lo = t * chunk;
    int hi = lo + chunk; if (hi > N) hi = N;
    int s = 0;
    for (int i = lo; i < hi; ++i) s += counts[i];
    sums[t] = s;
    __syncthreads();
    for (int off = 1; off < 1024; off <<= 1) {
        int v = (t >= off) ? sums[t - off] : 0;
        __syncthreads();
        sums[t] += v;
        __syncthreads();
    }
    int run = (t == 0) ? 0 : sums[t - 1];
    for (int i = lo; i < hi; ++i) {
        int c = counts[i];
        rowstart[i] = run;
        cursor[i] = run;
        dinv[i] = rsqrtf((float)(c + 1));
        run += c;
    }
    if (t == 1023) rowstart[N] = sums[1023];
}

__global__ void scatter_kernel(const void* __restrict__ ei, const int* __restrict__ flag,
                               int* __restrict__ cursor, const float* __restrict__ dinv,
                               int* __restrict__ csr_src, float* __restrict__ csr_norm,
                               int E, int N) {
    int e = blockIdx.x * blockDim.x + threadIdx.x;
    if (e >= E) return;
    int f64 = *flag;
    int s = idx_at(ei, e, f64);
    int d = idx_at(ei, (long long)E + e, f64);
    if ((unsigned)s >= (unsigned)N || (unsigned)d >= (unsigned)N) return;
    int pos = atomicAdd(&cursor[d], 1);
    csr_src[pos] = s;
    csr_norm[pos] = dinv[s] * dinv[d];
}

// out[i] = dinv[i]^2 * x[i] + sum_e norm_e * x[src_e]   (wave per node, float2/lane)
__global__ __launch_bounds__(256) void agg_kernel(const float* __restrict__ x,
                                                  const int* __restrict__ rowstart,
                                                  const int* __restrict__ csr_src,
                                                  const float* __restrict__ csr_norm,
                                                  const float* __restrict__ dinv,
                                                  float* __restrict__ out, int N) {
    int wid = (blockIdx.x * blockDim.x + threadIdx.x) >> 6;
    int lane = threadIdx.x & 63;
    if (wid >= N) return;
    const float2* x2 = (const float2*)x;
    float di = dinv[wid];
    float w0 = di * di;
    float2 xs = x2[(size_t)wid * 64 + lane];
    float accx = w0 * xs.x, accy = w0 * xs.y;
    int e0 = rowstart[wid], e1 = rowstart[wid + 1];
    for (int e = e0; e < e1; ++e) {
        int s = csr_src[e];
        float w = csr_norm[e];
        float2 v = x2[(size_t)s * 64 + lane];
        accx = fmaf(w, v.x, accx);
        accy = fmaf(w, v.y, accy);
    }
    float2 r; r.x = accx; r.y = accy;
    ((float2*)out)[(size_t)wid * 64 + lane] = r;
}

// O = relu(A @ W + bias), A:[M][128], W:[128][128]. 128x128 tile, 8x8 microtile.
__global__ __launch_bounds__(256) void gemm_bias_relu(const float* __restrict__ A,
                                                      const float* __restrict__ W,
                                                      const float* __restrict__ bias,
                                                      float* __restrict__ O, int M) {
    __shared__ float As[32][128];  // As[k][r] (transposed)
    __shared__ float Ws[32][128];  // Ws[k][c]
    int t = threadIdx.x;
    int tx = t & 15, ty = t >> 4;
    int r0 = ty * 8, c0 = tx * 8;
    int blockRow = blockIdx.x * 128;
    float acc[8][8];
#pragma unroll
    for (int i = 0; i < 8; i++)
#pragma unroll
        for (int j = 0; j < 8; j++) acc[i][j] = 0.f;

    for (int k0 = 0; k0 < 128; k0 += 32) {
        __syncthreads();
        // stage A chunk (transpose): id = t + 256q; row=id>>3, kk4=id&7
#pragma unroll
        for (int q = 0; q < 4; ++q) {
            int id = t + 256 * q;
            int row = id >> 3, kk4 = id & 7;
            int grow = blockRow + row;
            float4 v = make_float4(0.f, 0.f, 0.f, 0.f);
            if (grow < M) v = *(const float4*)&A[(size_t)grow * 128 + k0 + kk4 * 4];
            As[kk4 * 4 + 0][row] = v.x;
            As[kk4 * 4 + 1][row] = v.y;
            As[kk4 * 4 + 2][row] = v.z;
            As[kk4 * 4 + 3][row] = v.w;
        }
        // stage W chunk: id = t + 256q; krow=id>>5, c4=id&31
#pragma unroll
        for (int q = 0; q < 4; ++q) {
            int id = t + 256 * q;
            int krow = id >> 5, c4 = id & 31;
            float4 v = *(const float4*)&W[(size_t)(k0 + krow) * 128 + c4 * 4];
            *(float4*)&Ws[krow][c4 * 4] = v;
        }
        __syncthreads();
#pragma unroll 4
        for (int k = 0; k < 32; ++k) {
            float4 a0 = *(const float4*)&As[k][r0];
            float4 a1 = *(const float4*)&As[k][r0 + 4];
            float4 b0 = *(const float4*)&Ws[k][c0];
            float4 b1 = *(const float4*)&Ws[k][c0 + 4];
            float a[8] = {a0.x, a0.y, a0.z, a0.w, a1.x, a1.y, a1.z, a1.w};
            float b[8] = {b0.x, b0.y, b0.z, b0.w, b1.x, b1.y, b1.z, b1.w};
#pragma unroll
            for (int i = 0; i < 8; i++)
#pragma unroll
                for (int j = 0; j < 8; j++) acc[i][j] = fmaf(a[i], b[j], acc[i][j]);
        }
    }
#pragma unroll
    for (int i = 0; i < 8; i++) {
        int gr = blockRow + r0 + i;
        if (gr >= M) break;
#pragma unroll
        for (int j = 0; j < 8; j += 4) {
            float4 o;
            o.x = fmaxf(acc[i][j + 0] + bias[c0 + j + 0], 0.f);
            o.y = fmaxf(acc[i][j + 1] + bias[c0 + j + 1], 0.f);
            o.z = fmaxf(acc[i][j + 2] + bias[c0 + j + 2], 0.f);
            o.w = fmaxf(acc[i][j + 3] + bias[c0 + j + 3], 0.f);
            *(float4*)&O[(size_t)gr * 128 + c0 + j] = o;
        }
    }
}

// batch is sorted: per block, running per-graph accumulation; atomic flush at
// graph boundaries. 128 threads = one per feature.
#define POOL_NODES 512
__global__ __launch_bounds__(128) void pool_kernel(const float* __restrict__ h,
                                                   const void* __restrict__ batch,
                                                   const int* __restrict__ flag,
                                                   float* __restrict__ pooled,
                                                   float* __restrict__ gcnt, int N) {
    int f = threadIdx.x;
    int n0 = blockIdx.x * POOL_NODES;
    if (n0 >= N) return;
    int n1 = n0 + POOL_NODES; if (n1 > N) n1 = N;
    int f64 = *flag;
    int g = idx_at(batch, n0, f64);
    float acc = 0.f;
    int cnt = 0;
    for (int n = n0; n < n1; ++n) {
        int gn = idx_at(batch, n, f64);
        if (gn != g) {
            if ((unsigned)g < (unsigned)NGRAPH) {
                atomicAdd(&pooled[g * HID + f], acc);
                if (f == 0) atomicAdd(&gcnt[g], (float)cnt);
            }
            acc = 0.f; cnt = 0; g = gn;
        }
        acc += h[(size_t)n * HID + f];
        cnt++;
    }
    if ((unsigned)g < (unsigned)NGRAPH) {
        atomicAdd(&pooled[g * HID + f], acc);
        if (f == 0) atomicAdd(&gcnt[g], (float)cnt);
    }
}

__global__ __launch_bounds__(128) void final_kernel(const float* __restrict__ pooled,
                                                    const float* __restrict__ gcnt,
                                                    const float* __restrict__ Wl,
                                                    const float* __restrict__ bl,
                                                    float* __restrict__ out) {
    int o = blockIdx.x * blockDim.x + threadIdx.x;
    if (o >= NGRAPH * 10) return;
    int g = o / 10, c = o % 10;
    float inv = 1.0f / fmaxf(gcnt[g], 1.0f);
    float acc = 0.f;
    for (int k = 0; k < HID; ++k)
        acc = fmaf(pooled[g * HID + k], Wl[k * 10 + c], acc);
    out[o] = acc * inv + bl[c];
}

extern "C" void kernel_launch(void* const* d_in, const int* in_sizes, int n_in,
                              void* d_out, int out_size, void* d_ws, size_t ws_size,
                              hipStream_t stream) {
    const float* x   = (const float*)d_in[0];
    const void* ei   = d_in[1];
    const void* bat  = d_in[2];
    const float* W1  = (const float*)d_in[3];
    const float* b1  = (const float*)d_in[4];
    const float* W2  = (const float*)d_in[5];
    const float* b2  = (const float*)d_in[6];
    const float* W3  = (const float*)d_in[7];
    const float* b3  = (const float*)d_in[8];
    const float* Wl  = (const float*)d_in[9];
    const float* bl  = (const float*)d_in[10];
    float* out = (float*)d_out;

    const int N = in_sizes[0] / HID;   // 50000
    const int E = in_sizes[1] / 2;     // 600000

    char* w = (char*)d_ws;
    size_t off = 0;
    auto carve = [&](size_t bytes) -> void* {
        void* p = w + off;
        off = (off + bytes + 255) & ~(size_t)255;
        return p;
    };
    float* bufA     = (float*)carve((size_t)N * HID * 4);
    float* bufB     = (float*)carve((size_t)N * HID * 4);
    int*   counts   = (int*)carve((size_t)N * 4);
    int*   rowstart = (int*)carve((size_t)(N + 1) * 4);
    int*   cursor   = (int*)carve((size_t)N * 4);
    float* dinv     = (float*)carve((size_t)N * 4);
    int*   csr_src  = (int*)carve((size_t)E * 4);
    float* csr_norm = (float*)carve((size_t)E * 4);
    float* pooled   = (float*)carve((size_t)NGRAPH * HID * 4);
    float* gcnt     = (float*)carve((size_t)NGRAPH * 4);
    int*   flag     = (int*)carve(256);

    // graph preprocessing (once; shared by all 3 layers)
    detect_kernel<<<1, 256, 0, stream>>>((const int*)ei, flag);
    init_kernel<<<(N + 255) / 256, 256, 0, stream>>>(counts, pooled, gcnt, N);
    hist_kernel<<<(E + 255) / 256, 256, 0, stream>>>(ei, flag, counts, E, N);
    scan_kernel<<<1, 1024, 0, stream>>>(counts, rowstart, cursor, dinv, N);
    scatter_kernel<<<(E + 255) / 256, 256, 0, stream>>>(ei, flag, cursor, dinv,
                                                        csr_src, csr_norm, E, N);

    int aggBlocks  = (N + 3) / 4;          // one wave per node, 4 waves/block
    int gemmBlocks = (N + 127) / 128;

    // layer 1: agg(x)->B, relu(B@W1+b1)->A
    agg_kernel<<<aggBlocks, 256, 0, stream>>>(x, rowstart, csr_src, csr_norm, dinv, bufB, N);
    gemm_bias_relu<<<gemmBlocks, 256, 0, stream>>>(bufB, W1, b1, bufA, N);
    // layer 2
    agg_kernel<<<aggBlocks, 256, 0, stream>>>(bufA, rowstart, csr_src, csr_norm, dinv, bufB, N);
    gemm_bias_relu<<<gemmBlocks, 256, 0, stream>>>(bufB, W2, b2, bufA, N);
    // layer 3
    agg_kernel<<<aggBlocks, 256, 0, stream>>>(bufA, rowstart, csr_src, csr_norm, dinv, bufB, N);
    gemm_bias_relu<<<gemmBlocks, 256, 0, stream>>>(bufB, W3, b3, bufA, N);

    // mean pool + final linear
    pool_kernel<<<(N + POOL_NODES - 1) / POOL_NODES, 128, 0, stream>>>(bufA, bat, flag,
                                                                       pooled, gcnt, N);
    final_kernel<<<5, 128, 0, stream>>>(pooled, gcnt, Wl, bl, out);
}

// Round 2
// 552.189 us; speedup vs baseline: 1.2201x; 1.2201x over previous
//
#include <hip/hip_runtime.h>
#include <hip/hip_bf16.h>

// ---------------------------------------------------------------------------
// GCN graph classifier: 3x GCNConv(128->128) + ReLU, mean-pool(64), linear(10)
// Strategy:
//   * Build CSR (by dst) + sym-norm once per call (graph identical across layers)
//   * Per layer: agg = A_norm * x  (pull-based gather, wave per node),
//                x' = relu(agg @ W + b)  (fp32 tiled GEMM, vector ALU)
//   * Pool: batch sorted -> wave per 16-node chunk, float2/lane, atomic flush
//     at graph boundaries (R1: was 1 block/512 nodes -> 2% occupancy, 152us)
//   * Final: (sums @ Wlin)/cnt + blin  -> out[64][10]
// ---------------------------------------------------------------------------

#define HID 128
#define NGRAPH 64

// runtime int32/int64 index accessor (reference declares int64; JAX default is
// int32 — detect on device and branch)
__device__ __forceinline__ int idx_at(const void* p, long long i, int f64) {
    if (f64) return (int)((const long long*)p)[i];
    return ((const int*)p)[i];
}

// Detect whether index arrays are int64: sample odd 32-bit words of edge_index;
// for little-endian int64 with values < 2^31 they are all zero.
__global__ void detect_kernel(const int* __restrict__ ei, int* __restrict__ flag) {
    __shared__ int cnt;
    if (threadIdx.x == 0) cnt = 0;
    __syncthreads();
    int z = 0;
    for (int i = threadIdx.x; i < 2048; i += 256)
        if (ei[2 * i + 1] == 0) z++;
    atomicAdd(&cnt, z);
    __syncthreads();
    if (threadIdx.x == 0) *flag = (cnt > 1024) ? 1 : 0;
}

__global__ void init_kernel(int* __restrict__ counts, float* __restrict__ pooled,
                            float* __restrict__ gcnt, int N) {
    int i = blockIdx.x * blockDim.x + threadIdx.x;
    if (i < N) counts[i] = 0;
    if (i < NGRAPH * HID) pooled[i] = 0.f;
    if (i < NGRAPH) gcnt[i] = 0.f;
}

__global__ void hist_kernel(const void* __restrict__ ei, const int* __restrict__ flag,
                            int* __restrict__ counts, int E, int N) {
    int e = blockIdx.x * blockDim.x + threadIdx.x;
    if (e >= E) return;
    int f64 = *flag;
    int d = idx_at(ei, (long long)E + e, f64);
    if ((unsigned)d < (unsigned)N) atomicAdd(&counts[d], 1);
}

// Single-block exclusive scan over counts[N] -> rowstart[N+1]; also fills
// cursor (copy of rowstart) and dinv = rsqrt(deg) with deg = counts+1 (self loop).
__global__ __launch_bounds__(1024) void scan_kernel(const int* __restrict__ counts,
                                                    int* __restrict__ rowstart,
                                                    int* __restrict__ cursor,
                                                    float* __restrict__ dinv, int N) {
    __shared__ int sums[1024];
    int t = threadIdx.x;
    int chunk = (N + 1023) >> 10;
    int lo = t * chunk;
    int hi = lo + chunk; if (hi > N) hi = N;
    int s = 0;
    for (int i = lo; i < hi; ++i) s += counts[i];
    sums[t] = s;
    __syncthreads();
    for (int off = 1; off < 1024; off <<= 1) {
        int v = (t >= off) ? sums[t - off] : 0;
        __syncthreads();
        sums[t] += v;
        __syncthreads();
    }
    int run = (t == 0) ? 0 : sums[t - 1];
    for (int i = lo; i < hi; ++i) {
        int c = counts[i];
        rowstart[i] = run;
        cursor[i] = run;
        dinv[i] = rsqrtf((float)(c + 1));
        run += c;
    }
    if (t == 1023) rowstart[N] = sums[1023];
}

__global__ void scatter_kernel(const void* __restrict__ ei, const int* __restrict__ flag,
                               int* __restrict__ cursor, const float* __restrict__ dinv,
                               int* __restrict__ csr_src, float* __restrict__ csr_norm,
                               int E, int N) {
    int e = blockIdx.x * blockDim.x + threadIdx.x;
    if (e >= E) return;
    int f64 = *flag;
    int s = idx_at(ei, e, f64);
    int d = idx_at(ei, (long long)E + e, f64);
    if ((unsigned)s >= (unsigned)N || (unsigned)d >= (unsigned)N) return;
    int pos = atomicAdd(&cursor[d], 1);
    csr_src[pos] = s;
    csr_norm[pos] = dinv[s] * dinv[d];
}

// out[i] = dinv[i]^2 * x[i] + sum_e norm_e * x[src_e]   (wave per node, float2/lane)
__global__ __launch_bounds__(256) void agg_kernel(const float* __restrict__ x,
                                                  const int* __restrict__ rowstart,
                                                  const int* __restrict__ csr_src,
                                                  const float* __restrict__ csr_norm,
                                                  const float* __restrict__ dinv,
                                                  float* __restrict__ out, int N) {
    int wid = (blockIdx.x * blockDim.x + threadIdx.x) >> 6;
    int lane = threadIdx.x & 63;
    if (wid >= N) return;
    const float2* x2 = (const float2*)x;
    float di = dinv[wid];
    float w0 = di * di;
    float2 xs = x2[(size_t)wid * 64 + lane];
    float accx = w0 * xs.x, accy = w0 * xs.y;
    int e0 = rowstart[wid], e1 = rowstart[wid + 1];
    for (int e = e0; e < e1; ++e) {
        int s = csr_src[e];
        float w = csr_norm[e];
        float2 v = x2[(size_t)s * 64 + lane];
        accx = fmaf(w, v.x, accx);
        accy = fmaf(w, v.y, accy);
    }
    float2 r; r.x = accx; r.y = accy;
    ((float2*)out)[(size_t)wid * 64 + lane] = r;
}

// O = relu(A @ W + bias), A:[M][128], W:[128][128]. 128x128 tile, 8x8 microtile.
__global__ __launch_bounds__(256) void gemm_bias_relu(const float* __restrict__ A,
                                                      const float* __restrict__ W,
                                                      const float* __restrict__ bias,
                                                      float* __restrict__ O, int M) {
    __shared__ float As[32][128];  // As[k][r] (transposed)
    __shared__ float Ws[32][128];  // Ws[k][c]
    int t = threadIdx.x;
    int tx = t & 15, ty = t >> 4;
    int r0 = ty * 8, c0 = tx * 8;
    int blockRow = blockIdx.x * 128;
    float acc[8][8];
#pragma unroll
    for (int i = 0; i < 8; i++)
#pragma unroll
        for (int j = 0; j < 8; j++) acc[i][j] = 0.f;

    for (int k0 = 0; k0 < 128; k0 += 32) {
        __syncthreads();
        // stage A chunk (transpose): id = t + 256q; row=id>>3, kk4=id&7
#pragma unroll
        for (int q = 0; q < 4; ++q) {
            int id = t + 256 * q;
            int row = id >> 3, kk4 = id & 7;
            int grow = blockRow + row;
            float4 v = make_float4(0.f, 0.f, 0.f, 0.f);
            if (grow < M) v = *(const float4*)&A[(size_t)grow * 128 + k0 + kk4 * 4];
            As[kk4 * 4 + 0][row] = v.x;
            As[kk4 * 4 + 1][row] = v.y;
            As[kk4 * 4 + 2][row] = v.z;
            As[kk4 * 4 + 3][row] = v.w;
        }
        // stage W chunk: id = t + 256q; krow=id>>5, c4=id&31
#pragma unroll
        for (int q = 0; q < 4; ++q) {
            int id = t + 256 * q;
            int krow = id >> 5, c4 = id & 31;
            float4 v = *(const float4*)&W[(size_t)(k0 + krow) * 128 + c4 * 4];
            *(float4*)&Ws[krow][c4 * 4] = v;
        }
        __syncthreads();
#pragma unroll 4
        for (int k = 0; k < 32; ++k) {
            float4 a0 = *(const float4*)&As[k][r0];
            float4 a1 = *(const float4*)&As[k][r0 + 4];
            float4 b0 = *(const float4*)&Ws[k][c0];
            float4 b1 = *(const float4*)&Ws[k][c0 + 4];
            float a[8] = {a0.x, a0.y, a0.z, a0.w, a1.x, a1.y, a1.z, a1.w};
            float b[8] = {b0.x, b0.y, b0.z, b0.w, b1.x, b1.y, b1.z, b1.w};
#pragma unroll
            for (int i = 0; i < 8; i++)
#pragma unroll
                for (int j = 0; j < 8; j++) acc[i][j] = fmaf(a[i], b[j], acc[i][j]);
        }
    }
#pragma unroll
    for (int i = 0; i < 8; i++) {
        int gr = blockRow + r0 + i;
        if (gr >= M) break;
#pragma unroll
        for (int j = 0; j < 8; j += 4) {
            float4 o;
            o.x = fmaxf(acc[i][j + 0] + bias[c0 + j + 0], 0.f);
            o.y = fmaxf(acc[i][j + 1] + bias[c0 + j + 1], 0.f);
            o.z = fmaxf(acc[i][j + 2] + bias[c0 + j + 2], 0.f);
            o.w = fmaxf(acc[i][j + 3] + bias[c0 + j + 3], 0.f);
            *(float4*)&O[(size_t)gr * 128 + c0 + j] = o;
        }
    }
}

// batch is sorted: one WAVE per 16-node chunk, float2 per lane (128 features),
// running per-graph accumulation in registers, atomic flush at graph
// boundaries. R1 rewrite: was 1 block per 512 nodes -> 2% occupancy, 152us.
#define POOL_CHUNK 16
__global__ __launch_bounds__(256) void pool_kernel(const float* __restrict__ h,
                                                   const void* __restrict__ batch,
                                                   const int* __restrict__ flag,
                                                   float* __restrict__ pooled,
                                                   float* __restrict__ gcnt, int N) {
    int wid = (blockIdx.x * blockDim.x + threadIdx.x) >> 6;
    int lane = threadIdx.x & 63;
    int n0 = wid * POOL_CHUNK;
    if (n0 >= N) return;
    int n1 = n0 + POOL_CHUNK; if (n1 > N) n1 = N;
    int f64 = *flag;
    const float2* h2 = (const float2*)h;
    int g = idx_at(batch, n0, f64);
    float ax = 0.f, ay = 0.f;
    int cnt = 0;
    for (int n = n0; n < n1; ++n) {
        int gn = idx_at(batch, n, f64);
        if (gn != g) {
            if ((unsigned)g < (unsigned)NGRAPH) {
                atomicAdd(&pooled[g * HID + 2 * lane], ax);
                atomicAdd(&pooled[g * HID + 2 * lane + 1], ay);
                if (lane == 0) atomicAdd(&gcnt[g], (float)cnt);
            }
            ax = ay = 0.f; cnt = 0; g = gn;
        }
        float2 v = h2[(size_t)n * 64 + lane];
        ax += v.x; ay += v.y; cnt++;
    }
    if ((unsigned)g < (unsigned)NGRAPH) {
        atomicAdd(&pooled[g * HID + 2 * lane], ax);
        atomicAdd(&pooled[g * HID + 2 * lane + 1], ay);
        if (lane == 0) atomicAdd(&gcnt[g], (float)cnt);
    }
}

__global__ __launch_bounds__(128) void final_kernel(const float* __restrict__ pooled,
                                                    const float* __restrict__ gcnt,
                                                    const float* __restrict__ Wl,
                                                    const float* __restrict__ bl,
                                                    float* __restrict__ out) {
    int o = blockIdx.x * blockDim.x + threadIdx.x;
    if (o >= NGRAPH * 10) return;
    int g = o / 10, c = o % 10;
    float inv = 1.0f / fmaxf(gcnt[g], 1.0f);
    float acc = 0.f;
    for (int k = 0; k < HID; ++k)
        acc = fmaf(pooled[g * HID + k], Wl[k * 10 + c], acc);
    out[o] = acc * inv + bl[c];
}

extern "C" void kernel_launch(void* const* d_in, const int* in_sizes, int n_in,
                              void* d_out, int out_size, void* d_ws, size_t ws_size,
                              hipStream_t stream) {
    const float* x   = (const float*)d_in[0];
    const void* ei   = d_in[1];
    const void* bat  = d_in[2];
    const float* W1  = (const float*)d_in[3];
    const float* b1  = (const float*)d_in[4];
    const float* W2  = (const float*)d_in[5];
    const float* b2  = (const float*)d_in[6];
    const float* W3  = (const float*)d_in[7];
    const float* b3  = (const float*)d_in[8];
    const float* Wl  = (const float*)d_in[9];
    const float* bl  = (const float*)d_in[10];
    float* out = (float*)d_out;

    const int N = in_sizes[0] / HID;   // 50000
    const int E = in_sizes[1] / 2;     // 600000

    char* w = (char*)d_ws;
    size_t off = 0;
    auto carve = [&](size_t bytes) -> void* {
        void* p = w + off;
        off = (off + bytes + 255) & ~(size_t)255;
        return p;
    };
    float* bufA     = (float*)carve((size_t)N * HID * 4);
    float* bufB     = (float*)carve((size_t)N * HID * 4);
    int*   counts   = (int*)carve((size_t)N * 4);
    int*   rowstart = (int*)carve((size_t)(N + 1) * 4);
    int*   cursor   = (int*)carve((size_t)N * 4);
    float* dinv     = (float*)carve((size_t)N * 4);
    int*   csr_src  = (int*)carve((size_t)E * 4);
    float* csr_norm = (float*)carve((size_t)E * 4);
    float* pooled   = (float*)carve((size_t)NGRAPH * HID * 4);
    float* gcnt     = (float*)carve((size_t)NGRAPH * 4);
    int*   flag     = (int*)carve(256);

    // graph preprocessing (once; shared by all 3 layers)
    detect_kernel<<<1, 256, 0, stream>>>((const int*)ei, flag);
    init_kernel<<<(N + 255) / 256, 256, 0, stream>>>(counts, pooled, gcnt, N);
    hist_kernel<<<(E + 255) / 256, 256, 0, stream>>>(ei, flag, counts, E, N);
    scan_kernel<<<1, 1024, 0, stream>>>(counts, rowstart, cursor, dinv, N);
    scatter_kernel<<<(E + 255) / 256, 256, 0, stream>>>(ei, flag, cursor, dinv,
                                                        csr_src, csr_norm, E, N);

    int aggBlocks  = (N + 3) / 4;          // one wave per node, 4 waves/block
    int gemmBlocks = (N + 127) / 128;

    // layer 1: agg(x)->B, relu(B@W1+b1)->A
    agg_kernel<<<aggBlocks, 256, 0, stream>>>(x, rowstart, csr_src, csr_norm, dinv, bufB, N);
    gemm_bias_relu<<<gemmBlocks, 256, 0, stream>>>(bufB, W1, b1, bufA, N);
    // layer 2
    agg_kernel<<<aggBlocks, 256, 0, stream>>>(bufA, rowstart, csr_src, csr_norm, dinv, bufB, N);
    gemm_bias_relu<<<gemmBlocks, 256, 0, stream>>>(bufB, W2, b2, bufA, N);
    // layer 3
    agg_kernel<<<aggBlocks, 256, 0, stream>>>(bufA, rowstart, csr_src, csr_norm, dinv, bufB, N);
    gemm_bias_relu<<<gemmBlocks, 256, 0, stream>>>(bufB, W3, b3, bufA, N);

    // mean pool + final linear
    int poolWaves = (N + POOL_CHUNK - 1) / POOL_CHUNK;
    int poolBlocks = (poolWaves + 3) / 4;
    pool_kernel<<<poolBlocks, 256, 0, stream>>>(bufA, bat, flag, pooled, gcnt, N);
    final_kernel<<<5, 128, 0, stream>>>(pooled, gcnt, Wl, bl, out);
}

// Round 3
// 425.081 us; speedup vs baseline: 1.5850x; 1.2990x over previous
//
#include <hip/hip_runtime.h>
#include <hip/hip_bf16.h>

// ---------------------------------------------------------------------------
// GCN graph classifier: 3x GCNConv(128->128) + ReLU, mean-pool(64), linear(10)
// Strategy:
//   * Build CSR (by dst) + sym-norm once per call (graph identical across layers)
//   * Per layer: agg = A_norm * x  (pull-based gather, wave per node),
//                x' = relu(agg @ W + b)  (fp32 tiled GEMM, vector ALU)
//   * Pool: batch sorted -> wave per 16-node chunk, float2/lane, atomic flush
//     at graph boundaries (R1: was 1 block/512 nodes -> 2% occupancy, 152us)
//   * Scan: 3-kernel parallel scan (R2: single-block scan was 137us at 0.14%
//     occupancy; now ~10us)
//   * Final: (sums @ Wlin)/cnt + blin  -> out[64][10]
// ---------------------------------------------------------------------------

#define HID 128
#define NGRAPH 64

// runtime int32/int64 index accessor (reference declares int64; JAX default is
// int32 — detect on device and branch)
__device__ __forceinline__ int idx_at(const void* p, long long i, int f64) {
    if (f64) return (int)((const long long*)p)[i];
    return ((const int*)p)[i];
}

// Detect whether index arrays are int64: sample odd 32-bit words of edge_index;
// for little-endian int64 with values < 2^31 they are all zero.
__global__ void detect_kernel(const int* __restrict__ ei, int* __restrict__ flag) {
    __shared__ int cnt;
    if (threadIdx.x == 0) cnt = 0;
    __syncthreads();
    int z = 0;
    for (int i = threadIdx.x; i < 2048; i += 256)
        if (ei[2 * i + 1] == 0) z++;
    atomicAdd(&cnt, z);
    __syncthreads();
    if (threadIdx.x == 0) *flag = (cnt > 1024) ? 1 : 0;
}

__global__ void init_kernel(int* __restrict__ counts, float* __restrict__ pooled,
                            float* __restrict__ gcnt, int N) {
    int i = blockIdx.x * blockDim.x + threadIdx.x;
    if (i < N) counts[i] = 0;
    if (i < NGRAPH * HID) pooled[i] = 0.f;
    if (i < NGRAPH) gcnt[i] = 0.f;
}

__global__ void hist_kernel(const void* __restrict__ ei, const int* __restrict__ flag,
                            int* __restrict__ counts, int E, int N) {
    int e = blockIdx.x * blockDim.x + threadIdx.x;
    if (e >= E) return;
    int f64 = *flag;
    int d = idx_at(ei, (long long)E + e, f64);
    if ((unsigned)d < (unsigned)N) atomicAdd(&counts[d], 1);
}

__device__ __forceinline__ int wave_incl_scan(int v, int lane) {
#pragma unroll
    for (int off = 1; off < 64; off <<= 1) {
        int u = __shfl_up(v, off);
        if (lane >= off) v += u;
    }
    return v;
}

// ---- 3-kernel parallel exclusive scan over counts[N] (R2) ----
// A: per-block (256-elem) sums
__global__ __launch_bounds__(256) void blocksum_kernel(const int* __restrict__ counts,
                                                       int* __restrict__ bsums, int N) {
    int i = blockIdx.x * 256 + threadIdx.x;
    int v = (i < N) ? counts[i] : 0;
    int lane = threadIdx.x & 63, w = threadIdx.x >> 6;
#pragma unroll
    for (int off = 32; off > 0; off >>= 1) v += __shfl_down(v, off);
    __shared__ int ws[4];
    if (lane == 0) ws[w] = v;
    __syncthreads();
    if (threadIdx.x == 0) bsums[blockIdx.x] = ws[0] + ws[1] + ws[2] + ws[3];
}

// B: exclusive scan of the nb (<=256) block sums, in place
__global__ __launch_bounds__(256) void scanb_kernel(int* __restrict__ bsums, int nb) {
    int t = threadIdx.x;
    int lane = t & 63, w = t >> 6;
    int v = (t < nb) ? bsums[t] : 0;
    int iv = wave_incl_scan(v, lane);
    __shared__ int wsum[4];
    if (lane == 63) wsum[w] = iv;
    __syncthreads();
    int add = 0;
    for (int k = 0; k < w; ++k) add += wsum[k];
    if (t < nb) bsums[t] = iv - v + add;  // exclusive
}

// C: in-block exclusive scan + block offset -> rowstart/cursor/dinv
__global__ __launch_bounds__(256) void fill_kernel(const int* __restrict__ counts,
                                                   const int* __restrict__ bsums,
                                                   int* __restrict__ rowstart,
                                                   int* __restrict__ cursor,
                                                   float* __restrict__ dinv, int N) {
    int i = blockIdx.x * 256 + threadIdx.x;
    int c = (i < N) ? counts[i] : 0;
    int lane = threadIdx.x & 63, w = threadIdx.x >> 6;
    int iv = wave_incl_scan(c, lane);
    __shared__ int wsum[4];
    if (lane == 63) wsum[w] = iv;
    __syncthreads();
    int add = bsums[blockIdx.x];
    for (int k = 0; k < w; ++k) add += wsum[k];
    int excl = iv - c + add;
    if (i < N) {
        rowstart[i] = excl;
        cursor[i] = excl;
        dinv[i] = rsqrtf((float)(c + 1));
        if (i == N - 1) rowstart[N] = excl + c;
    }
}

__global__ void scatter_kernel(const void* __restrict__ ei, const int* __restrict__ flag,
                               int* __restrict__ cursor, const float* __restrict__ dinv,
                               int* __restrict__ csr_src, float* __restrict__ csr_norm,
                               int E, int N) {
    int e = blockIdx.x * blockDim.x + threadIdx.x;
    if (e >= E) return;
    int f64 = *flag;
    int s = idx_at(ei, e, f64);
    int d = idx_at(ei, (long long)E + e, f64);
    if ((unsigned)s >= (unsigned)N || (unsigned)d >= (unsigned)N) return;
    int pos = atomicAdd(&cursor[d], 1);
    csr_src[pos] = s;
    csr_norm[pos] = dinv[s] * dinv[d];
}

// out[i] = dinv[i]^2 * x[i] + sum_e norm_e * x[src_e]   (wave per node, float2/lane)
__global__ __launch_bounds__(256) void agg_kernel(const float* __restrict__ x,
                                                  const int* __restrict__ rowstart,
                                                  const int* __restrict__ csr_src,
                                                  const float* __restrict__ csr_norm,
                                                  const float* __restrict__ dinv,
                                                  float* __restrict__ out, int N) {
    int wid = (blockIdx.x * blockDim.x + threadIdx.x) >> 6;
    int lane = threadIdx.x & 63;
    if (wid >= N) return;
    const float2* x2 = (const float2*)x;
    float di = dinv[wid];
    float w0 = di * di;
    float2 xs = x2[(size_t)wid * 64 + lane];
    float accx = w0 * xs.x, accy = w0 * xs.y;
    int e0 = rowstart[wid], e1 = rowstart[wid + 1];
    for (int e = e0; e < e1; ++e) {
        int s = csr_src[e];
        float w = csr_norm[e];
        float2 v = x2[(size_t)s * 64 + lane];
        accx = fmaf(w, v.x, accx);
        accy = fmaf(w, v.y, accy);
    }
    float2 r; r.x = accx; r.y = accy;
    ((float2*)out)[(size_t)wid * 64 + lane] = r;
}

// O = relu(A @ W + bias), A:[M][128], W:[128][128]. 128x128 tile, 8x8 microtile.
__global__ __launch_bounds__(256) void gemm_bias_relu(const float* __restrict__ A,
                                                      const float* __restrict__ W,
                                                      const float* __restrict__ bias,
                                                      float* __restrict__ O, int M) {
    __shared__ float As[32][128];  // As[k][r] (transposed)
    __shared__ float Ws[32][128];  // Ws[k][c]
    int t = threadIdx.x;
    int tx = t & 15, ty = t >> 4;
    int r0 = ty * 8, c0 = tx * 8;
    int blockRow = blockIdx.x * 128;
    float acc[8][8];
#pragma unroll
    for (int i = 0; i < 8; i++)
#pragma unroll
        for (int j = 0; j < 8; j++) acc[i][j] = 0.f;

    for (int k0 = 0; k0 < 128; k0 += 32) {
        __syncthreads();
        // stage A chunk (transpose): id = t + 256q; row=id>>3, kk4=id&7
#pragma unroll
        for (int q = 0; q < 4; ++q) {
            int id = t + 256 * q;
            int row = id >> 3, kk4 = id & 7;
            int grow = blockRow + row;
            float4 v = make_float4(0.f, 0.f, 0.f, 0.f);
            if (grow < M) v = *(const float4*)&A[(size_t)grow * 128 + k0 + kk4 * 4];
            As[kk4 * 4 + 0][row] = v.x;
            As[kk4 * 4 + 1][row] = v.y;
            As[kk4 * 4 + 2][row] = v.z;
            As[kk4 * 4 + 3][row] = v.w;
        }
        // stage W chunk: id = t + 256q; krow=id>>5, c4=id&31
#pragma unroll
        for (int q = 0; q < 4; ++q) {
            int id = t + 256 * q;
            int krow = id >> 5, c4 = id & 31;
            float4 v = *(const float4*)&W[(size_t)(k0 + krow) * 128 + c4 * 4];
            *(float4*)&Ws[krow][c4 * 4] = v;
        }
        __syncthreads();
#pragma unroll 4
        for (int k = 0; k < 32; ++k) {
            float4 a0 = *(const float4*)&As[k][r0];
            float4 a1 = *(const float4*)&As[k][r0 + 4];
            float4 b0 = *(const float4*)&Ws[k][c0];
            float4 b1 = *(const float4*)&Ws[k][c0 + 4];
            float a[8] = {a0.x, a0.y, a0.z, a0.w, a1.x, a1.y, a1.z, a1.w};
            float b[8] = {b0.x, b0.y, b0.z, b0.w, b1.x, b1.y, b1.z, b1.w};
#pragma unroll
            for (int i = 0; i < 8; i++)
#pragma unroll
                for (int j = 0; j < 8; j++) acc[i][j] = fmaf(a[i], b[j], acc[i][j]);
        }
    }
#pragma unroll
    for (int i = 0; i < 8; i++) {
        int gr = blockRow + r0 + i;
        if (gr >= M) break;
#pragma unroll
        for (int j = 0; j < 8; j += 4) {
            float4 o;
            o.x = fmaxf(acc[i][j + 0] + bias[c0 + j + 0], 0.f);
            o.y = fmaxf(acc[i][j + 1] + bias[c0 + j + 1], 0.f);
            o.z = fmaxf(acc[i][j + 2] + bias[c0 + j + 2], 0.f);
            o.w = fmaxf(acc[i][j + 3] + bias[c0 + j + 3], 0.f);
            *(float4*)&O[(size_t)gr * 128 + c0 + j] = o;
        }
    }
}

// batch is sorted: one WAVE per 16-node chunk, float2 per lane (128 features),
// running per-graph accumulation in registers, atomic flush at graph
// boundaries. R1 rewrite: was 1 block per 512 nodes -> 2% occupancy, 152us.
#define POOL_CHUNK 16
__global__ __launch_bounds__(256) void pool_kernel(const float* __restrict__ h,
                                                   const void* __restrict__ batch,
                                                   const int* __restrict__ flag,
                                                   float* __restrict__ pooled,
                                                   float* __restrict__ gcnt, int N) {
    int wid = (blockIdx.x * blockDim.x + threadIdx.x) >> 6;
    int lane = threadIdx.x & 63;
    int n0 = wid * POOL_CHUNK;
    if (n0 >= N) return;
    int n1 = n0 + POOL_CHUNK; if (n1 > N) n1 = N;
    int f64 = *flag;
    const float2* h2 = (const float2*)h;
    int g = idx_at(batch, n0, f64);
    float ax = 0.f, ay = 0.f;
    int cnt = 0;
    for (int n = n0; n < n1; ++n) {
        int gn = idx_at(batch, n, f64);
        if (gn != g) {
            if ((unsigned)g < (unsigned)NGRAPH) {
                atomicAdd(&pooled[g * HID + 2 * lane], ax);
                atomicAdd(&pooled[g * HID + 2 * lane + 1], ay);
                if (lane == 0) atomicAdd(&gcnt[g], (float)cnt);
            }
            ax = ay = 0.f; cnt = 0; g = gn;
        }
        float2 v = h2[(size_t)n * 64 + lane];
        ax += v.x; ay += v.y; cnt++;
    }
    if ((unsigned)g < (unsigned)NGRAPH) {
        atomicAdd(&pooled[g * HID + 2 * lane], ax);
        atomicAdd(&pooled[g * HID + 2 * lane + 1], ay);
        if (lane == 0) atomicAdd(&gcnt[g], (float)cnt);
    }
}

__global__ __launch_bounds__(128) void final_kernel(const float* __restrict__ pooled,
                                                    const float* __restrict__ gcnt,
                                                    const float* __restrict__ Wl,
                                                    const float* __restrict__ bl,
                                                    float* __restrict__ out) {
    int o = blockIdx.x * blockDim.x + threadIdx.x;
    if (o >= NGRAPH * 10) return;
    int g = o / 10, c = o % 10;
    float inv = 1.0f / fmaxf(gcnt[g], 1.0f);
    float acc = 0.f;
    for (int k = 0; k < HID; ++k)
        acc = fmaf(pooled[g * HID + k], Wl[k * 10 + c], acc);
    out[o] = acc * inv + bl[c];
}

extern "C" void kernel_launch(void* const* d_in, const int* in_sizes, int n_in,
                              void* d_out, int out_size, void* d_ws, size_t ws_size,
                              hipStream_t stream) {
    const float* x   = (const float*)d_in[0];
    const void* ei   = d_in[1];
    const void* bat  = d_in[2];
    const float* W1  = (const float*)d_in[3];
    const float* b1  = (const float*)d_in[4];
    const float* W2  = (const float*)d_in[5];
    const float* b2  = (const float*)d_in[6];
    const float* W3  = (const float*)d_in[7];
    const float* b3  = (const float*)d_in[8];
    const float* Wl  = (const float*)d_in[9];
    const float* bl  = (const float*)d_in[10];
    float* out = (float*)d_out;

    const int N = in_sizes[0] / HID;   // 50000
    const int E = in_sizes[1] / 2;     // 600000

    char* w = (char*)d_ws;
    size_t off = 0;
    auto carve = [&](size_t bytes) -> void* {
        void* p = w + off;
        off = (off + bytes + 255) & ~(size_t)255;
        return p;
    };
    float* bufA     = (float*)carve((size_t)N * HID * 4);
    float* bufB     = (float*)carve((size_t)N * HID * 4);
    int*   counts   = (int*)carve((size_t)N * 4);
    int*   rowstart = (int*)carve((size_t)(N + 1) * 4);
    int*   cursor   = (int*)carve((size_t)N * 4);
    float* dinv     = (float*)carve((size_t)N * 4);
    int*   csr_src  = (int*)carve((size_t)E * 4);
    float* csr_norm = (float*)carve((size_t)E * 4);
    float* pooled   = (float*)carve((size_t)NGRAPH * HID * 4);
    float* gcnt     = (float*)carve((size_t)NGRAPH * 4);
    int*   bsums    = (int*)carve(1024);
    int*   flag     = (int*)carve(256);

    const int nb = (N + 255) / 256;  // scan blocks (196 for N=50000)

    // graph preprocessing (once; shared by all 3 layers)
    detect_kernel<<<1, 256, 0, stream>>>((const int*)ei, flag);
    init_kernel<<<(N + 255) / 256, 256, 0, stream>>>(counts, pooled, gcnt, N);
    hist_kernel<<<(E + 255) / 256, 256, 0, stream>>>(ei, flag, counts, E, N);
    blocksum_kernel<<<nb, 256, 0, stream>>>(counts, bsums, N);
    scanb_kernel<<<1, 256, 0, stream>>>(bsums, nb);
    fill_kernel<<<nb, 256, 0, stream>>>(counts, bsums, rowstart, cursor, dinv, N);
    scatter_kernel<<<(E + 255) / 256, 256, 0, stream>>>(ei, flag, cursor, dinv,
                                                        csr_src, csr_norm, E, N);

    int aggBlocks  = (N + 3) / 4;          // one wave per node, 4 waves/block
    int gemmBlocks = (N + 127) / 128;

    // layer 1: agg(x)->B, relu(B@W1+b1)->A
    agg_kernel<<<aggBlocks, 256, 0, stream>>>(x, rowstart, csr_src, csr_norm, dinv, bufB, N);
    gemm_bias_relu<<<gemmBlocks, 256, 0, stream>>>(bufB, W1, b1, bufA, N);
    // layer 2
    agg_kernel<<<aggBlocks, 256, 0, stream>>>(bufA, rowstart, csr_src, csr_norm, dinv, bufB, N);
    gemm_bias_relu<<<gemmBlocks, 256, 0, stream>>>(bufB, W2, b2, bufA, N);
    // layer 3
    agg_kernel<<<aggBlocks, 256, 0, stream>>>(bufA, rowstart, csr_src, csr_norm, dinv, bufB, N);
    gemm_bias_relu<<<gemmBlocks, 256, 0, stream>>>(bufB, W3, b3, bufA, N);

    // mean pool + final linear
    int poolWaves = (N + POOL_CHUNK - 1) / POOL_CHUNK;
    int poolBlocks = (poolWaves + 3) / 4;
    pool_kernel<<<poolBlocks, 256, 0, stream>>>(bufA, bat, flag, pooled, gcnt, N);
    final_kernel<<<5, 128, 0, stream>>>(pooled, gcnt, Wl, bl, out);
}

// Round 4
// 364.024 us; speedup vs baseline: 1.8508x; 1.1677x over previous
//
#include <hip/hip_runtime.h>
#include <hip/hip_bf16.h>

// ---------------------------------------------------------------------------
// GCN graph classifier: 3x GCNConv(128->128) + ReLU, mean-pool(64), linear(10)
// Strategy:
//   * Build CSR (by dst) + sym-norm once per call (graph identical across layers)
//   * Per layer: agg = A_norm * x  (pull-based gather, wave per node),
//                x' = relu(agg @ W + b)  (fp32 tiled GEMM, vector ALU)
//   * Pool: batch sorted -> wave per 16-node chunk, float2/lane, atomic flush
//     at graph boundaries (R1: was 1 block/512 nodes -> 2% occupancy, 152us)
//   * Scan: 3-kernel parallel scan (R2: single-block scan was 137us at 0.14%
//     occupancy; now ~10us)
//   * Agg: edge loop unrolled x4, 4 independent row-gathers in flight per wave
//     (R3: serial dependent chain was latency-bound at 2.4 TB/s L2-miss BW)
//   * Final: (sums @ Wlin)/cnt + blin  -> out[64][10]
// ---------------------------------------------------------------------------

#define HID 128
#define NGRAPH 64

// runtime int32/int64 index accessor (reference declares int64; JAX default is
// int32 — detect on device and branch)
__device__ __forceinline__ int idx_at(const void* p, long long i, int f64) {
    if (f64) return (int)((const long long*)p)[i];
    return ((const int*)p)[i];
}

// Detect whether index arrays are int64: sample odd 32-bit words of edge_index;
// for little-endian int64 with values < 2^31 they are all zero.
__global__ void detect_kernel(const int* __restrict__ ei, int* __restrict__ flag) {
    __shared__ int cnt;
    if (threadIdx.x == 0) cnt = 0;
    __syncthreads();
    int z = 0;
    for (int i = threadIdx.x; i < 2048; i += 256)
        if (ei[2 * i + 1] == 0) z++;
    atomicAdd(&cnt, z);
    __syncthreads();
    if (threadIdx.x == 0) *flag = (cnt > 1024) ? 1 : 0;
}

__global__ void init_kernel(int* __restrict__ counts, float* __restrict__ pooled,
                            float* __restrict__ gcnt, int N) {
    int i = blockIdx.x * blockDim.x + threadIdx.x;
    if (i < N) counts[i] = 0;
    if (i < NGRAPH * HID) pooled[i] = 0.f;
    if (i < NGRAPH) gcnt[i] = 0.f;
}

__global__ void hist_kernel(const void* __restrict__ ei, const int* __restrict__ flag,
                            int* __restrict__ counts, int E, int N) {
    int e = blockIdx.x * blockDim.x + threadIdx.x;
    if (e >= E) return;
    int f64 = *flag;
    int d = idx_at(ei, (long long)E + e, f64);
    if ((unsigned)d < (unsigned)N) atomicAdd(&counts[d], 1);
}

__device__ __forceinline__ int wave_incl_scan(int v, int lane) {
#pragma unroll
    for (int off = 1; off < 64; off <<= 1) {
        int u = __shfl_up(v, off);
        if (lane >= off) v += u;
    }
    return v;
}

// ---- 3-kernel parallel exclusive scan over counts[N] (R2) ----
// A: per-block (256-elem) sums
__global__ __launch_bounds__(256) void blocksum_kernel(const int* __restrict__ counts,
                                                       int* __restrict__ bsums, int N) {
    int i = blockIdx.x * 256 + threadIdx.x;
    int v = (i < N) ? counts[i] : 0;
    int lane = threadIdx.x & 63, w = threadIdx.x >> 6;
#pragma unroll
    for (int off = 32; off > 0; off >>= 1) v += __shfl_down(v, off);
    __shared__ int ws[4];
    if (lane == 0) ws[w] = v;
    __syncthreads();
    if (threadIdx.x == 0) bsums[blockIdx.x] = ws[0] + ws[1] + ws[2] + ws[3];
}

// B: exclusive scan of the nb (<=256) block sums, in place
__global__ __launch_bounds__(256) void scanb_kernel(int* __restrict__ bsums, int nb) {
    int t = threadIdx.x;
    int lane = t & 63, w = t >> 6;
    int v = (t < nb) ? bsums[t] : 0;
    int iv = wave_incl_scan(v, lane);
    __shared__ int wsum[4];
    if (lane == 63) wsum[w] = iv;
    __syncthreads();
    int add = 0;
    for (int k = 0; k < w; ++k) add += wsum[k];
    if (t < nb) bsums[t] = iv - v + add;  // exclusive
}

// C: in-block exclusive scan + block offset -> rowstart/cursor/dinv
__global__ __launch_bounds__(256) void fill_kernel(const int* __restrict__ counts,
                                                   const int* __restrict__ bsums,
                                                   int* __restrict__ rowstart,
                                                   int* __restrict__ cursor,
                                                   float* __restrict__ dinv, int N) {
    int i = blockIdx.x * 256 + threadIdx.x;
    int c = (i < N) ? counts[i] : 0;
    int lane = threadIdx.x & 63, w = threadIdx.x >> 6;
    int iv = wave_incl_scan(c, lane);
    __shared__ int wsum[4];
    if (lane == 63) wsum[w] = iv;
    __syncthreads();
    int add = bsums[blockIdx.x];
    for (int k = 0; k < w; ++k) add += wsum[k];
    int excl = iv - c + add;
    if (i < N) {
        rowstart[i] = excl;
        cursor[i] = excl;
        dinv[i] = rsqrtf((float)(c + 1));
        if (i == N - 1) rowstart[N] = excl + c;
    }
}

__global__ void scatter_kernel(const void* __restrict__ ei, const int* __restrict__ flag,
                               int* __restrict__ cursor, const float* __restrict__ dinv,
                               int* __restrict__ csr_src, float* __restrict__ csr_norm,
                               int E, int N) {
    int e = blockIdx.x * blockDim.x + threadIdx.x;
    if (e >= E) return;
    int f64 = *flag;
    int s = idx_at(ei, e, f64);
    int d = idx_at(ei, (long long)E + e, f64);
    if ((unsigned)s >= (unsigned)N || (unsigned)d >= (unsigned)N) return;
    int pos = atomicAdd(&cursor[d], 1);
    csr_src[pos] = s;
    csr_norm[pos] = dinv[s] * dinv[d];
}

// out[i] = dinv[i]^2 * x[i] + sum_e norm_e * x[src_e]   (wave per node, float2/lane)
// R3: edge loop unrolled x4 -> 4 independent 512B row-gathers in flight per
// wave (was 1; latency-bound). Dual accumulators for FMA ILP.
__global__ __launch_bounds__(256) void agg_kernel(const float* __restrict__ x,
                                                  const int* __restrict__ rowstart,
                                                  const int* __restrict__ csr_src,
                                                  const float* __restrict__ csr_norm,
                                                  const float* __restrict__ dinv,
                                                  float* __restrict__ out, int N) {
    int wid = (blockIdx.x * blockDim.x + threadIdx.x) >> 6;
    int lane = threadIdx.x & 63;
    if (wid >= N) return;
    const float2* x2 = (const float2*)x;
    float di = dinv[wid];
    float w0 = di * di;
    float2 xs = x2[(size_t)wid * 64 + lane];
    float accx = w0 * xs.x, accy = w0 * xs.y;
    float bccx = 0.f, bccy = 0.f;
    int e0 = rowstart[wid], e1 = rowstart[wid + 1];
    int e = e0;
    for (; e + 4 <= e1; e += 4) {
        int s0 = csr_src[e + 0];
        int s1 = csr_src[e + 1];
        int s2 = csr_src[e + 2];
        int s3 = csr_src[e + 3];
        float wa = csr_norm[e + 0];
        float wb = csr_norm[e + 1];
        float wc = csr_norm[e + 2];
        float wd = csr_norm[e + 3];
        float2 v0 = x2[(size_t)s0 * 64 + lane];
        float2 v1 = x2[(size_t)s1 * 64 + lane];
        float2 v2 = x2[(size_t)s2 * 64 + lane];
        float2 v3 = x2[(size_t)s3 * 64 + lane];
        accx = fmaf(wa, v0.x, accx); accy = fmaf(wa, v0.y, accy);
        bccx = fmaf(wb, v1.x, bccx); bccy = fmaf(wb, v1.y, bccy);
        accx = fmaf(wc, v2.x, accx); accy = fmaf(wc, v2.y, accy);
        bccx = fmaf(wd, v3.x, bccx); bccy = fmaf(wd, v3.y, bccy);
    }
    for (; e < e1; ++e) {
        int s = csr_src[e];
        float w = csr_norm[e];
        float2 v = x2[(size_t)s * 64 + lane];
        accx = fmaf(w, v.x, accx);
        accy = fmaf(w, v.y, accy);
    }
    float2 r; r.x = accx + bccx; r.y = accy + bccy;
    ((float2*)out)[(size_t)wid * 64 + lane] = r;
}

// O = relu(A @ W + bias), A:[M][128], W:[128][128]. 128x128 tile, 8x8 microtile.
__global__ __launch_bounds__(256) void gemm_bias_relu(const float* __restrict__ A,
                                                      const float* __restrict__ W,
                                                      const float* __restrict__ bias,
                                                      float* __restrict__ O, int M) {
    __shared__ float As[32][128];  // As[k][r] (transposed)
    __shared__ float Ws[32][128];  // Ws[k][c]
    int t = threadIdx.x;
    int tx = t & 15, ty = t >> 4;
    int r0 = ty * 8, c0 = tx * 8;
    int blockRow = blockIdx.x * 128;
    float acc[8][8];
#pragma unroll
    for (int i = 0; i < 8; i++)
#pragma unroll
        for (int j = 0; j < 8; j++) acc[i][j] = 0.f;

    for (int k0 = 0; k0 < 128; k0 += 32) {
        __syncthreads();
        // stage A chunk (transpose): id = t + 256q; row=id>>3, kk4=id&7
#pragma unroll
        for (int q = 0; q < 4; ++q) {
            int id = t + 256 * q;
            int row = id >> 3, kk4 = id & 7;
            int grow = blockRow + row;
            float4 v = make_float4(0.f, 0.f, 0.f, 0.f);
            if (grow < M) v = *(const float4*)&A[(size_t)grow * 128 + k0 + kk4 * 4];
            As[kk4 * 4 + 0][row] = v.x;
            As[kk4 * 4 + 1][row] = v.y;
            As[kk4 * 4 + 2][row] = v.z;
            As[kk4 * 4 + 3][row] = v.w;
        }
        // stage W chunk: id = t + 256q; krow=id>>5, c4=id&31
#pragma unroll
        for (int q = 0; q < 4; ++q) {
            int id = t + 256 * q;
            int krow = id >> 5, c4 = id & 31;
            float4 v = *(const float4*)&W[(size_t)(k0 + krow) * 128 + c4 * 4];
            *(float4*)&Ws[krow][c4 * 4] = v;
        }
        __syncthreads();
#pragma unroll 4
        for (int k = 0; k < 32; ++k) {
            float4 a0 = *(const float4*)&As[k][r0];
            float4 a1 = *(const float4*)&As[k][r0 + 4];
            float4 b0 = *(const float4*)&Ws[k][c0];
            float4 b1 = *(const float4*)&Ws[k][c0 + 4];
            float a[8] = {a0.x, a0.y, a0.z, a0.w, a1.x, a1.y, a1.z, a1.w};
            float b[8] = {b0.x, b0.y, b0.z, b0.w, b1.x, b1.y, b1.z, b1.w};
#pragma unroll
            for (int i = 0; i < 8; i++)
#pragma unroll
                for (int j = 0; j < 8; j++) acc[i][j] = fmaf(a[i], b[j], acc[i][j]);
        }
    }
#pragma unroll
    for (int i = 0; i < 8; i++) {
        int gr = blockRow + r0 + i;
        if (gr >= M) break;
#pragma unroll
        for (int j = 0; j < 8; j += 4) {
            float4 o;
            o.x = fmaxf(acc[i][j + 0] + bias[c0 + j + 0], 0.f);
            o.y = fmaxf(acc[i][j + 1] + bias[c0 + j + 1], 0.f);
            o.z = fmaxf(acc[i][j + 2] + bias[c0 + j + 2], 0.f);
            o.w = fmaxf(acc[i][j + 3] + bias[c0 + j + 3], 0.f);
            *(float4*)&O[(size_t)gr * 128 + c0 + j] = o;
        }
    }
}

// batch is sorted: one WAVE per 16-node chunk, float2 per lane (128 features),
// running per-graph accumulation in registers, atomic flush at graph
// boundaries. R1 rewrite: was 1 block per 512 nodes -> 2% occupancy, 152us.
#define POOL_CHUNK 16
__global__ __launch_bounds__(256) void pool_kernel(const float* __restrict__ h,
                                                   const void* __restrict__ batch,
                                                   const int* __restrict__ flag,
                                                   float* __restrict__ pooled,
                                                   float* __restrict__ gcnt, int N) {
    int wid = (blockIdx.x * blockDim.x + threadIdx.x) >> 6;
    int lane = threadIdx.x & 63;
    int n0 = wid * POOL_CHUNK;
    if (n0 >= N) return;
    int n1 = n0 + POOL_CHUNK; if (n1 > N) n1 = N;
    int f64 = *flag;
    const float2* h2 = (const float2*)h;
    int g = idx_at(batch, n0, f64);
    float ax = 0.f, ay = 0.f;
    int cnt = 0;
    for (int n = n0; n < n1; ++n) {
        int gn = idx_at(batch, n, f64);
        if (gn != g) {
            if ((unsigned)g < (unsigned)NGRAPH) {
                atomicAdd(&pooled[g * HID + 2 * lane], ax);
                atomicAdd(&pooled[g * HID + 2 * lane + 1], ay);
                if (lane == 0) atomicAdd(&gcnt[g], (float)cnt);
            }
            ax = ay = 0.f; cnt = 0; g = gn;
        }
        float2 v = h2[(size_t)n * 64 + lane];
        ax += v.x; ay += v.y; cnt++;
    }
    if ((unsigned)g < (unsigned)NGRAPH) {
        atomicAdd(&pooled[g * HID + 2 * lane], ax);
        atomicAdd(&pooled[g * HID + 2 * lane + 1], ay);
        if (lane == 0) atomicAdd(&gcnt[g], (float)cnt);
    }
}

__global__ __launch_bounds__(128) void final_kernel(const float* __restrict__ pooled,
                                                    const float* __restrict__ gcnt,
                                                    const float* __restrict__ Wl,
                                                    const float* __restrict__ bl,
                                                    float* __restrict__ out) {
    int o = blockIdx.x * blockDim.x + threadIdx.x;
    if (o >= NGRAPH * 10) return;
    int g = o / 10, c = o % 10;
    float inv = 1.0f / fmaxf(gcnt[g], 1.0f);
    float acc = 0.f;
    for (int k = 0; k < HID; ++k)
        acc = fmaf(pooled[g * HID + k], Wl[k * 10 + c], acc);
    out[o] = acc * inv + bl[c];
}

extern "C" void kernel_launch(void* const* d_in, const int* in_sizes, int n_in,
                              void* d_out, int out_size, void* d_ws, size_t ws_size,
                              hipStream_t stream) {
    const float* x   = (const float*)d_in[0];
    const void* ei   = d_in[1];
    const void* bat  = d_in[2];
    const float* W1  = (const float*)d_in[3];
    const float* b1  = (const float*)d_in[4];
    const float* W2  = (const float*)d_in[5];
    const float* b2  = (const float*)d_in[6];
    const float* W3  = (const float*)d_in[7];
    const float* b3  = (const float*)d_in[8];
    const float* Wl  = (const float*)d_in[9];
    const float* bl  = (const float*)d_in[10];
    float* out = (float*)d_out;

    const int N = in_sizes[0] / HID;   // 50000
    const int E = in_sizes[1] / 2;     // 600000

    char* w = (char*)d_ws;
    size_t off = 0;
    auto carve = [&](size_t bytes) -> void* {
        void* p = w + off;
        off = (off + bytes + 255) & ~(size_t)255;
        return p;
    };
    float* bufA     = (float*)carve((size_t)N * HID * 4);
    float* bufB     = (float*)carve((size_t)N * HID * 4);
    int*   counts   = (int*)carve((size_t)N * 4);
    int*   rowstart = (int*)carve((size_t)(N + 1) * 4);
    int*   cursor   = (int*)carve((size_t)N * 4);
    float* dinv     = (float*)carve((size_t)N * 4);
    int*   csr_src  = (int*)carve((size_t)E * 4);
    float* csr_norm = (float*)carve((size_t)E * 4);
    float* pooled   = (float*)carve((size_t)NGRAPH * HID * 4);
    float* gcnt    = (float*)carve((size_t)NGRAPH * 4);
    int*   bsums    = (int*)carve(1024);
    int*   flag     = (int*)carve(256);

    const int nb = (N + 255) / 256;  // scan blocks (196 for N=50000)

    // graph preprocessing (once; shared by all 3 layers)
    detect_kernel<<<1, 256, 0, stream>>>((const int*)ei, flag);
    init_kernel<<<(N + 255) / 256, 256, 0, stream>>>(counts, pooled, gcnt, N);
    hist_kernel<<<(E + 255) / 256, 256, 0, stream>>>(ei, flag, counts, E, N);
    blocksum_kernel<<<nb, 256, 0, stream>>>(counts, bsums, N);
    scanb_kernel<<<1, 256, 0, stream>>>(bsums, nb);
    fill_kernel<<<nb, 256, 0, stream>>>(counts, bsums, rowstart, cursor, dinv, N);
    scatter_kernel<<<(E + 255) / 256, 256, 0, stream>>>(ei, flag, cursor, dinv,
                                                        csr_src, csr_norm, E, N);

    int aggBlocks  = (N + 3) / 4;          // one wave per node, 4 waves/block
    int gemmBlocks = (N + 127) / 128;

    // layer 1: agg(x)->B, relu(B@W1+b1)->A
    agg_kernel<<<aggBlocks, 256, 0, stream>>>(x, rowstart, csr_src, csr_norm, dinv, bufB, N);
    gemm_bias_relu<<<gemmBlocks, 256, 0, stream>>>(bufB, W1, b1, bufA, N);
    // layer 2
    agg_kernel<<<aggBlocks, 256, 0, stream>>>(bufA, rowstart, csr_src, csr_norm, dinv, bufB, N);
    gemm_bias_relu<<<gemmBlocks, 256, 0, stream>>>(bufB, W2, b2, bufA, N);
    // layer 3
    agg_kernel<<<aggBlocks, 256, 0, stream>>>(bufA, rowstart, csr_src, csr_norm, dinv, bufB, N);
    gemm_bias_relu<<<gemmBlocks, 256, 0, stream>>>(bufB, W3, b3, bufA, N);

    // mean pool + final linear
    int poolWaves = (N + POOL_CHUNK - 1) / POOL_CHUNK;
    int poolBlocks = (poolWaves + 3) / 4;
    pool_kernel<<<poolBlocks, 256, 0, stream>>>(bufA, bat, flag, pooled, gcnt, N);
    final_kernel<<<5, 128, 0, stream>>>(pooled, gcnt, Wl, bl, out);
}